// Round 1
// baseline (363.010 us; speedup 1.0000x reference)
//
#include <hip/hip_runtime.h>
#include <math.h>

#define B_ 4
#define T_ 4096
#define E_ 1024
#define H_ 128

typedef __attribute__((ext_vector_type(8))) short short8;
typedef __attribute__((ext_vector_type(4))) float f32x4;

__device__ __forceinline__ unsigned short f2bf(float f) {
    union { float f; unsigned int u; } v; v.f = f;
    unsigned int r = v.u + 0x7fffu + ((v.u >> 16) & 1u);
    return (unsigned short)(r >> 16);
}

// ---------------------------------------------------------------------------
// Kernel 1: W[E][H] fp32  ->  Wt[H][E] bf16   (B-operand wants n-major rows)
// ---------------------------------------------------------------------------
__global__ void prep_w_kernel(const float* __restrict__ Wk,
                              const float* __restrict__ Wq,
                              const float* __restrict__ Wv,
                              unsigned short* __restrict__ Wt) {
    int sel = blockIdx.y;
    const float* W = (sel == 0) ? Wk : ((sel == 1) ? Wq : Wv);
    unsigned short* out = Wt + (size_t)sel * (E_ * H_);
    int idx = blockIdx.x * blockDim.x + threadIdx.x;
    if (idx < E_ * H_) {
        int e = idx >> 7;          // / H_
        int h = idx & (H_ - 1);
        out[(size_t)h * E_ + e] = f2bf(W[idx]);
    }
}

// ---------------------------------------------------------------------------
// Kernel 2: projection GEMM  P = X @ W  (fp32 in, bf16 out)
//   sel 0: kp [B*T,H]   sel 1: qp [B*T,H] * H^-0.5   sel 2: vpt [B][H][T]
// ---------------------------------------------------------------------------
__launch_bounds__(256)
__global__ void proj_kernel(const float* __restrict__ Xk,
                            const float* __restrict__ Xq,
                            const float* __restrict__ Xv,
                            const unsigned short* __restrict__ Wt,
                            unsigned short* __restrict__ kp,
                            unsigned short* __restrict__ qp,
                            unsigned short* __restrict__ vpt) {
    int sel = blockIdx.y;
    const float* X = (sel == 0) ? Xk : ((sel == 1) ? Xq : Xv);
    const unsigned short* W = Wt + (size_t)sel * (E_ * H_);

    __shared__ __align__(16) unsigned short Xs[64][72];
    __shared__ __align__(16) unsigned short Ws[128][72];

    int t = threadIdx.x;
    int wave = t >> 6, lane = t & 63;
    int l15 = lane & 15, quad = lane >> 4;
    int m0 = blockIdx.x * 64;

    f32x4 acc[8];
#pragma unroll
    for (int i = 0; i < 8; i++)
#pragma unroll
        for (int j = 0; j < 4; j++) acc[i][j] = 0.0f;

    for (int k0 = 0; k0 < E_; k0 += 64) {
#pragma unroll
        for (int i = 0; i < 4; i++) {
            int id = t + i * 256;
            int row = id >> 4, c4 = (id & 15) * 4;
            const float4 xv = *(const float4*)(X + (size_t)(m0 + row) * E_ + k0 + c4);
            unsigned int p0 = (unsigned int)f2bf(xv.x) | ((unsigned int)f2bf(xv.y) << 16);
            unsigned int p1 = (unsigned int)f2bf(xv.z) | ((unsigned int)f2bf(xv.w) << 16);
            *(uint2*)&Xs[row][c4] = make_uint2(p0, p1);
        }
#pragma unroll
        for (int i = 0; i < 4; i++) {
            int id = t + i * 256;
            int row = id >> 3, c8 = (id & 7) * 8;
            *(uint4*)&Ws[row][c8] = *(const uint4*)(W + (size_t)row * E_ + k0 + c8);
        }
        __syncthreads();
#pragma unroll
        for (int kk = 0; kk < 64; kk += 32) {
            short8 a = *(const short8*)&Xs[wave * 16 + l15][kk + quad * 8];
#pragma unroll
            for (int nt = 0; nt < 8; nt++) {
                short8 b = *(const short8*)&Ws[nt * 16 + l15][kk + quad * 8];
                acc[nt] = __builtin_amdgcn_mfma_f32_16x16x32_bf16(a, b, acc[nt], 0, 0, 0);
            }
        }
        __syncthreads();
    }

    if (sel < 2) {
        float scale = (sel == 1) ? 0.08838834764831845f : 1.0f;
        unsigned short* out = (sel == 0) ? kp : qp;
#pragma unroll
        for (int nt = 0; nt < 8; nt++)
#pragma unroll
            for (int r = 0; r < 4; r++) {
                int rowg = m0 + wave * 16 + quad * 4 + r;
                int col = nt * 16 + l15;
                out[(size_t)rowg * H_ + col] = f2bf(acc[nt][r] * scale);
            }
    } else {
#pragma unroll
        for (int nt = 0; nt < 8; nt++)
#pragma unroll
            for (int r = 0; r < 4; r++) {
                int rowg = m0 + wave * 16 + quad * 4 + r;
                int b = rowg >> 12;
                int tt = rowg & (T_ - 1);
                int col = nt * 16 + l15;
                vpt[(size_t)b * H_ * T_ + (size_t)col * T_ + tt] = f2bf(acc[nt][r]);
            }
    }
}

// ---------------------------------------------------------------------------
// Kernel 3: flash attention (causal), bf16 MFMA, fp32 out
// ---------------------------------------------------------------------------
__launch_bounds__(256)
__global__ void attn_kernel(const unsigned short* __restrict__ kp,
                            const unsigned short* __restrict__ qp,
                            const unsigned short* __restrict__ vpt,
                            float* __restrict__ out) {
    __shared__ __align__(16) unsigned short Qs[64][136];
    __shared__ __align__(16) unsigned short Ks[64][136];
    __shared__ __align__(16) unsigned short Vs[128][72];
    __shared__ __align__(16) unsigned short Ps[4][16][72];

    int t = threadIdx.x;
    int wave = t >> 6, lane = t & 63;
    int l15 = lane & 15, quad = lane >> 4;
    int b = blockIdx.y;
    int qt = blockIdx.x;
    int q0 = qt * 64;

    const unsigned short* qbase = qp + (size_t)b * T_ * H_ + (size_t)q0 * H_;
    const unsigned short* kbase = kp + (size_t)b * T_ * H_;
    const unsigned short* vbase = vpt + (size_t)b * H_ * T_;

#pragma unroll
    for (int i = 0; i < 4; i++) {
        int id = t + i * 256;
        int row = id >> 4, c8 = (id & 15) * 8;
        *(uint4*)&Qs[row][c8] = *(const uint4*)(qbase + (size_t)row * H_ + c8);
    }

    f32x4 acc_o[8];
#pragma unroll
    for (int i = 0; i < 8; i++)
#pragma unroll
        for (int j = 0; j < 4; j++) acc_o[i][j] = 0.0f;
    float m_i[4], l_i[4];
#pragma unroll
    for (int r = 0; r < 4; r++) { m_i[r] = -INFINITY; l_i[r] = 0.0f; }

    int nkt = qt + 1;
    for (int kt = 0; kt < nkt; kt++) {
        int k0 = kt * 64;
#pragma unroll
        for (int i = 0; i < 4; i++) {
            int id = t + i * 256;
            int row = id >> 4, c8 = (id & 15) * 8;
            *(uint4*)&Ks[row][c8] = *(const uint4*)(kbase + (size_t)(k0 + row) * H_ + c8);
        }
#pragma unroll
        for (int i = 0; i < 4; i++) {
            int id = t + i * 256;
            int row = id >> 3, c8 = (id & 7) * 8;
            *(uint4*)&Vs[row][c8] = *(const uint4*)(vbase + (size_t)row * T_ + k0 + c8);
        }
        __syncthreads();

        f32x4 s[4];
#pragma unroll
        for (int nt = 0; nt < 4; nt++)
#pragma unroll
            for (int j = 0; j < 4; j++) s[nt][j] = 0.0f;
#pragma unroll
        for (int kk = 0; kk < 128; kk += 32) {
            short8 a = *(const short8*)&Qs[wave * 16 + l15][kk + quad * 8];
#pragma unroll
            for (int nt = 0; nt < 4; nt++) {
                short8 bf = *(const short8*)&Ks[nt * 16 + l15][kk + quad * 8];
                s[nt] = __builtin_amdgcn_mfma_f32_16x16x32_bf16(a, bf, s[nt], 0, 0, 0);
            }
        }

        if (kt == qt) {
#pragma unroll
            for (int nt = 0; nt < 4; nt++) {
                int col = nt * 16 + l15;
#pragma unroll
                for (int r = 0; r < 4; r++) {
                    int row = wave * 16 + quad * 4 + r;
                    if (col > row) s[nt][r] = -INFINITY;
                }
            }
        }

        float mnew[4], alpha[4], rsum[4];
#pragma unroll
        for (int r = 0; r < 4; r++) {
            float v = fmaxf(fmaxf(s[0][r], s[1][r]), fmaxf(s[2][r], s[3][r]));
#pragma unroll
            for (int off = 8; off >= 1; off >>= 1) v = fmaxf(v, __shfl_xor(v, off, 16));
            mnew[r] = fmaxf(m_i[r], v);
            alpha[r] = __expf(m_i[r] - mnew[r]);
            m_i[r] = mnew[r];
            rsum[r] = 0.0f;
        }
#pragma unroll
        for (int nt = 0; nt < 4; nt++) {
            int col = nt * 16 + l15;
#pragma unroll
            for (int r = 0; r < 4; r++) {
                float p = __expf(s[nt][r] - mnew[r]);
                rsum[r] += p;
                Ps[wave][quad * 4 + r][col] = f2bf(p);
            }
        }
#pragma unroll
        for (int r = 0; r < 4; r++) {
            float v = rsum[r];
#pragma unroll
            for (int off = 8; off >= 1; off >>= 1) v += __shfl_xor(v, off, 16);
            l_i[r] = l_i[r] * alpha[r] + v;
        }
#pragma unroll
        for (int nt = 0; nt < 8; nt++)
#pragma unroll
            for (int r = 0; r < 4; r++) acc_o[nt][r] *= alpha[r];

#pragma unroll
        for (int kk = 0; kk < 64; kk += 32) {
            short8 a = *(const short8*)&Ps[wave][l15][kk + quad * 8];
#pragma unroll
            for (int nt = 0; nt < 8; nt++) {
                short8 bf = *(const short8*)&Vs[nt * 16 + l15][kk + quad * 8];
                acc_o[nt] = __builtin_amdgcn_mfma_f32_16x16x32_bf16(a, bf, acc_o[nt], 0, 0, 0);
            }
        }
        __syncthreads();
    }

    float* obase = out + (size_t)b * T_ * H_ + (size_t)q0 * H_;
#pragma unroll
    for (int r = 0; r < 4; r++) {
        float inv = 1.0f / l_i[r];
        int row = wave * 16 + quad * 4 + r;
#pragma unroll
        for (int nt = 0; nt < 8; nt++) {
            obase[(size_t)row * H_ + nt * 16 + l15] = acc_o[nt][r] * inv;
        }
    }
}

// ---------------------------------------------------------------------------
extern "C" void kernel_launch(void* const* d_in, const int* in_sizes, int n_in,
                              void* d_out, int out_size, void* d_ws, size_t ws_size,
                              hipStream_t stream) {
    (void)in_sizes; (void)n_in; (void)out_size; (void)ws_size;
    const float* k  = (const float*)d_in[0];
    const float* q  = (const float*)d_in[1];
    const float* v  = (const float*)d_in[2];
    const float* Wk = (const float*)d_in[3];
    const float* Wq = (const float*)d_in[4];
    const float* Wv = (const float*)d_in[5];

    unsigned short* wsu = (unsigned short*)d_ws;
    const size_t PROJ_ELEMS = (size_t)B_ * T_ * H_;
    unsigned short* kp  = wsu;
    unsigned short* qp  = wsu + PROJ_ELEMS;
    unsigned short* vpt = wsu + 2 * PROJ_ELEMS;
    unsigned short* Wt  = wsu + 3 * PROJ_ELEMS;

    prep_w_kernel<<<dim3((E_ * H_ + 255) / 256, 3), 256, 0, stream>>>(Wk, Wq, Wv, Wt);
    proj_kernel<<<dim3((B_ * T_) / 64, 3), 256, 0, stream>>>(k, q, v, Wt, kp, qp, vpt);
    attn_kernel<<<dim3(T_ / 64, B_), 256, 0, stream>>>(kp, qp, vpt, (float*)d_out);
}

// Round 2
// 327.259 us; speedup vs baseline: 1.1092x; 1.1092x over previous
//
#include <hip/hip_runtime.h>
#include <math.h>

#define B_ 4
#define T_ 4096
#define E_ 1024
#define H_ 128
#define S_ 4          // attention split-K factor

typedef __attribute__((ext_vector_type(8))) short short8;
typedef __attribute__((ext_vector_type(4))) float f32x4;
typedef unsigned short ushort;

__device__ __forceinline__ ushort f2bf(float f) {
    union { float f; unsigned int u; } v; v.f = f;
    unsigned int r = v.u + 0x7fffu + ((v.u >> 16) & 1u);
    return (ushort)(r >> 16);
}
__device__ __forceinline__ float bf2f(ushort u) {
    union { unsigned int u; float f; } v; v.u = ((unsigned int)u) << 16;
    return v.f;
}

typedef __attribute__((address_space(3))) unsigned int lds_u32;
typedef __attribute__((address_space(1))) const unsigned int g_u32;
__device__ __forceinline__ void gload_lds16(const ushort* g, ushort* l) {
    __builtin_amdgcn_global_load_lds((g_u32*)g, (lds_u32*)l, 16, 0, 0);
}

// ---------------------------------------------------------------------------
// Kernel 1: W[E][H] fp32 -> Wt[H][E] bf16
// ---------------------------------------------------------------------------
__global__ void prep_w_kernel(const float* __restrict__ Wk,
                              const float* __restrict__ Wq,
                              const float* __restrict__ Wv,
                              ushort* __restrict__ Wt) {
    int sel = blockIdx.y;
    const float* W = (sel == 0) ? Wk : ((sel == 1) ? Wq : Wv);
    ushort* out = Wt + (size_t)sel * (E_ * H_);
    int idx = blockIdx.x * blockDim.x + threadIdx.x;
    if (idx < E_ * H_) {
        int e = idx >> 7;
        int h = idx & (H_ - 1);
        out[(size_t)h * E_ + e] = f2bf(W[idx]);
    }
}

// ---------------------------------------------------------------------------
// Kernel 2: projection GEMM, M-tile 128, wave = 32 rows (2m x 8n blocking)
// ---------------------------------------------------------------------------
__launch_bounds__(256)
__global__ void proj_kernel(const float* __restrict__ Xk,
                            const float* __restrict__ Xq,
                            const float* __restrict__ Xv,
                            const ushort* __restrict__ Wt,
                            ushort* __restrict__ kp,
                            ushort* __restrict__ qp,
                            ushort* __restrict__ vpt) {
    int sel = blockIdx.y;
    const float* X = (sel == 0) ? Xk : ((sel == 1) ? Xq : Xv);
    const ushort* W = Wt + (size_t)sel * (E_ * H_);

    __shared__ __align__(16) ushort smem[17408];   // Xs[128][72] + Ws[128*64]; reused as [128][136]
    ushort* Xs = smem;            // padded, stride 72
    ushort* Ws = smem + 9216;     // unpadded, XOR-swizzled 8x16B chunks per row

    int t = threadIdx.x;
    int wave = t >> 6, lane = t & 63;
    int l15 = lane & 15, quad = lane >> 4;
    int m0 = blockIdx.x * 128;

    float4 xr[8];
    auto loadX = [&](int k0) {
#pragma unroll
        for (int i = 0; i < 8; i++)
            xr[i] = *(const float4*)(X + (size_t)(m0 + (t >> 4) + i * 16) * E_ + k0 + (t & 15) * 4);
    };
    auto loadW = [&](int k0) {
#pragma unroll
        for (int i = 0; i < 4; i++) {
            int slot = i * 256 + t;
            int row = slot >> 3, jst = slot & 7;
            int jsrc = jst ^ (row & 7);
            gload_lds16(W + (size_t)row * E_ + k0 + jsrc * 8, &Ws[slot * 8]);
        }
    };

    loadW(0);
    loadX(0);

    f32x4 acc[2][8];
#pragma unroll
    for (int mt = 0; mt < 2; mt++)
#pragma unroll
        for (int nt = 0; nt < 8; nt++)
#pragma unroll
            for (int j = 0; j < 4; j++) acc[mt][nt][j] = 0.0f;

    for (int k0 = 0; k0 < E_; k0 += 64) {
#pragma unroll
        for (int i = 0; i < 8; i++) {
            int row = (t >> 4) + i * 16, c4 = (t & 15) * 4;
            unsigned int p0 = (unsigned int)f2bf(xr[i].x) | ((unsigned int)f2bf(xr[i].y) << 16);
            unsigned int p1 = (unsigned int)f2bf(xr[i].z) | ((unsigned int)f2bf(xr[i].w) << 16);
            *(uint2*)&Xs[row * 72 + c4] = make_uint2(p0, p1);
        }
        __syncthreads();
        if (k0 + 64 < E_) loadX(k0 + 64);
#pragma unroll
        for (int ks = 0; ks < 2; ks++) {
            int kk = ks * 32;
            short8 a0 = *(const short8*)&Xs[(wave * 32 + l15) * 72 + kk + quad * 8];
            short8 a1 = *(const short8*)&Xs[(wave * 32 + 16 + l15) * 72 + kk + quad * 8];
#pragma unroll
            for (int nt = 0; nt < 8; nt++) {
                int n = nt * 16 + l15;
                int jj = (ks * 4 + quad) ^ (n & 7);
                short8 b = *(const short8*)&Ws[n * 64 + jj * 8];
                acc[0][nt] = __builtin_amdgcn_mfma_f32_16x16x32_bf16(a0, b, acc[0][nt], 0, 0, 0);
                acc[1][nt] = __builtin_amdgcn_mfma_f32_16x16x32_bf16(a1, b, acc[1][nt], 0, 0, 0);
            }
        }
        __syncthreads();
        if (k0 + 64 < E_) loadW(k0 + 64);
    }

    if (sel < 2) {
        float scale = (sel == 1) ? 0.08838834764831845f : 1.0f;
        ushort* out = (sel == 0) ? kp : qp;
#pragma unroll
        for (int mt = 0; mt < 2; mt++)
#pragma unroll
            for (int nt = 0; nt < 8; nt++)
#pragma unroll
                for (int r = 0; r < 4; r++) {
                    int row = m0 + wave * 32 + mt * 16 + quad * 4 + r;
                    out[(size_t)row * H_ + nt * 16 + l15] = f2bf(acc[mt][nt][r] * scale);
                }
    } else {
        // transpose through LDS for coalesced [b][h][t] stores
#pragma unroll
        for (int mt = 0; mt < 2; mt++)
#pragma unroll
            for (int nt = 0; nt < 8; nt++)
#pragma unroll
                for (int r = 0; r < 4; r++) {
                    int rowl = wave * 32 + mt * 16 + quad * 4 + r;
                    int col = nt * 16 + l15;
                    smem[col * 136 + rowl] = f2bf(acc[mt][nt][r]);
                }
        __syncthreads();
        int b = m0 >> 12;
        int t0 = m0 & (T_ - 1);
        ushort* dst = vpt + (size_t)b * H_ * T_ + (size_t)(t >> 1) * T_ + t0 + (t & 1) * 64;
        const ushort* srcl = &smem[(t >> 1) * 136 + (t & 1) * 64];
#pragma unroll
        for (int j = 0; j < 8; j++)
            *(uint4*)(dst + j * 8) = *(const uint4*)(srcl + j * 8);
    }
}

// ---------------------------------------------------------------------------
// Kernel 3: flash attention partials, split-K S_=4, Q-tile 128, K-tile 64
// wave = 32 Q rows; Q in registers; XOR-swizzled K/V via global_load_lds
// ---------------------------------------------------------------------------
__launch_bounds__(256)
__global__ void attn_kernel(const ushort* __restrict__ kp,
                            const ushort* __restrict__ qp,
                            const ushort* __restrict__ vpt,
                            ushort* __restrict__ Opart,
                            float* __restrict__ Mpart,
                            float* __restrict__ Lpart) {
    __shared__ __align__(16) ushort Ks[64 * 128];    // 16KB, 16 chunks/row, swizzled
    __shared__ __align__(16) ushort Vs[128 * 64];    // 16KB, 8 chunks/row, swizzled
    __shared__ __align__(16) ushort Ps[4 * 32 * 72]; // per-wave P, padded stride 72

    int t = threadIdx.x;
    int wave = t >> 6, lane = t & 63;
    int l15 = lane & 15, quad = lane >> 4;
    int s = blockIdx.x;
    int qt = blockIdx.y;
    int b = blockIdx.z;
    int q0 = qt * 128;
    int nkt = 2 * qt + 2;

    const ushort* kbase = kp + (size_t)b * T_ * H_;
    const ushort* vbase = vpt + (size_t)b * H_ * T_;

    // Q fragments -> registers (wave rows q0 + wave*32 + mt*16 + l15)
    short8 qf[2][4];
#pragma unroll
    for (int mt = 0; mt < 2; mt++)
#pragma unroll
        for (int ks = 0; ks < 4; ks++)
            qf[mt][ks] = *(const short8*)(qp + ((size_t)(b * T_ + q0 + wave * 32 + mt * 16 + l15)) * H_
                                             + ks * 32 + quad * 8);

    f32x4 acc_o[2][8];
#pragma unroll
    for (int mt = 0; mt < 2; mt++)
#pragma unroll
        for (int ht = 0; ht < 8; ht++)
#pragma unroll
            for (int j = 0; j < 4; j++) acc_o[mt][ht][j] = 0.0f;
    float m_i[2][4], l_i[2][4];
#pragma unroll
    for (int mt = 0; mt < 2; mt++)
#pragma unroll
        for (int r = 0; r < 4; r++) { m_i[mt][r] = -INFINITY; l_i[mt][r] = 0.0f; }

    for (int kt = s; kt < nkt; kt += S_) {
        int k0 = kt * 64;
        // stage K tile (64 rows x 16 chunks), swizzled
#pragma unroll
        for (int i = 0; i < 4; i++) {
            int slot = i * 256 + t;
            int row = slot >> 4, jst = slot & 15;
            int jsrc = jst ^ (row & 15);
            gload_lds16(kbase + (size_t)(k0 + row) * H_ + jsrc * 8, &Ks[slot * 8]);
        }
        // stage V tile (128 h-rows x 8 chunks), swizzled
#pragma unroll
        for (int i = 0; i < 4; i++) {
            int slot = i * 256 + t;
            int row = slot >> 3, jst = slot & 7;
            int jsrc = jst ^ (row & 7);
            gload_lds16(vbase + (size_t)row * T_ + k0 + jsrc * 8, &Vs[slot * 8]);
        }
        __syncthreads();   // drains vmcnt in each issuing wave -> tiles visible

        // S = Q K^T
        f32x4 sc[2][4];
#pragma unroll
        for (int mt = 0; mt < 2; mt++)
#pragma unroll
            for (int nt = 0; nt < 4; nt++)
#pragma unroll
                for (int j = 0; j < 4; j++) sc[mt][nt][j] = 0.0f;
#pragma unroll
        for (int ks = 0; ks < 4; ks++) {
#pragma unroll
            for (int nt = 0; nt < 4; nt++) {
                int n = nt * 16 + l15;
                int jj = (ks * 4 + quad) ^ (n & 15);
                short8 bf = *(const short8*)&Ks[n * 128 + jj * 8];
                sc[0][nt] = __builtin_amdgcn_mfma_f32_16x16x32_bf16(qf[0][ks], bf, sc[0][nt], 0, 0, 0);
                sc[1][nt] = __builtin_amdgcn_mfma_f32_16x16x32_bf16(qf[1][ks], bf, sc[1][nt], 0, 0, 0);
            }
        }

        // causal mask (only tiles near the diagonal)
        if (k0 + 63 > q0 + wave * 32) {
#pragma unroll
            for (int mt = 0; mt < 2; mt++)
#pragma unroll
                for (int nt = 0; nt < 4; nt++) {
                    int colg = k0 + nt * 16 + l15;
#pragma unroll
                    for (int r = 0; r < 4; r++) {
                        int rowg = q0 + wave * 32 + mt * 16 + quad * 4 + r;
                        if (colg > rowg) sc[mt][nt][r] = -INFINITY;
                    }
                }
        }

        // online softmax (rows live on 16 lanes of each quad)
        float alpha[2][4];
#pragma unroll
        for (int mt = 0; mt < 2; mt++)
#pragma unroll
            for (int r = 0; r < 4; r++) {
                float rowmax = fmaxf(fmaxf(sc[mt][0][r], sc[mt][1][r]),
                                     fmaxf(sc[mt][2][r], sc[mt][3][r]));
#pragma unroll
                for (int off = 8; off >= 1; off >>= 1)
                    rowmax = fmaxf(rowmax, __shfl_xor(rowmax, off, 16));
                float mnew = fmaxf(m_i[mt][r], rowmax);
                float msafe = fmaxf(mnew, -1e30f);
                float a = __expf(m_i[mt][r] - msafe);
                alpha[mt][r] = a;
                m_i[mt][r] = mnew;
                float rsum = 0.0f;
#pragma unroll
                for (int nt = 0; nt < 4; nt++) {
                    float p = __expf(sc[mt][nt][r] - msafe);
                    rsum += p;
                    Ps[wave * 2304 + (mt * 16 + quad * 4 + r) * 72 + nt * 16 + l15] = f2bf(p);
                }
#pragma unroll
                for (int off = 8; off >= 1; off >>= 1)
                    rsum += __shfl_xor(rsum, off, 16);
                l_i[mt][r] = l_i[mt][r] * a + rsum;
            }
#pragma unroll
        for (int mt = 0; mt < 2; mt++)
#pragma unroll
            for (int ht = 0; ht < 8; ht++)
#pragma unroll
                for (int r = 0; r < 4; r++) acc_o[mt][ht][r] *= alpha[mt][r];

        // O += P V   (P read back from own-wave LDS region; no barrier needed)
#pragma unroll
        for (int ks2 = 0; ks2 < 2; ks2++) {
            short8 a0 = *(const short8*)&Ps[wave * 2304 + (l15) * 72 + ks2 * 32 + quad * 8];
            short8 a1 = *(const short8*)&Ps[wave * 2304 + (16 + l15) * 72 + ks2 * 32 + quad * 8];
#pragma unroll
            for (int ht = 0; ht < 8; ht++) {
                int h = ht * 16 + l15;
                int jj = (ks2 * 4 + quad) ^ (h & 7);
                short8 bf = *(const short8*)&Vs[h * 64 + jj * 8];
                acc_o[0][ht] = __builtin_amdgcn_mfma_f32_16x16x32_bf16(a0, bf, acc_o[0][ht], 0, 0, 0);
                acc_o[1][ht] = __builtin_amdgcn_mfma_f32_16x16x32_bf16(a1, bf, acc_o[1][ht], 0, 0, 0);
            }
        }
        __syncthreads();   // protect Ks/Vs before next staging
    }

    // epilogue: write unnormalized partials
    const size_t BT = (size_t)B_ * T_;
#pragma unroll
    for (int mt = 0; mt < 2; mt++)
#pragma unroll
        for (int r = 0; r < 4; r++) {
            int grow = b * T_ + q0 + wave * 32 + mt * 16 + quad * 4 + r;
            if (l15 == 0) {
                Mpart[(size_t)s * BT + grow] = m_i[mt][r];
                Lpart[(size_t)s * BT + grow] = l_i[mt][r];
            }
#pragma unroll
            for (int ht = 0; ht < 8; ht++)
                Opart[((size_t)s * BT + grow) * H_ + ht * 16 + l15] = f2bf(acc_o[mt][ht][r]);
        }
}

// ---------------------------------------------------------------------------
// Kernel 4: combine split-K partials
// ---------------------------------------------------------------------------
__launch_bounds__(256)
__global__ void combine_kernel(const ushort* __restrict__ Opart,
                               const float* __restrict__ Mpart,
                               const float* __restrict__ Lpart,
                               float* __restrict__ out) {
    int t = threadIdx.x;
    int row = blockIdx.x * 2 + (t >> 7);
    int col = t & 127;
    const size_t BT = (size_t)B_ * T_;
    float m[S_], l[S_];
#pragma unroll
    for (int s = 0; s < S_; s++) {
        m[s] = Mpart[(size_t)s * BT + row];
        l[s] = Lpart[(size_t)s * BT + row];
    }
    float M = fmaxf(fmaxf(m[0], m[1]), fmaxf(m[2], m[3]));
    float den = 0.0f, acc = 0.0f;
#pragma unroll
    for (int s = 0; s < S_; s++) {
        float w = __expf(m[s] - M);
        den += l[s] * w;
        acc += w * bf2f(Opart[((size_t)s * BT + row) * H_ + col]);
    }
    out[(size_t)row * H_ + col] = acc / den;
}

// ---------------------------------------------------------------------------
extern "C" void kernel_launch(void* const* d_in, const int* in_sizes, int n_in,
                              void* d_out, int out_size, void* d_ws, size_t ws_size,
                              hipStream_t stream) {
    (void)in_sizes; (void)n_in; (void)out_size; (void)ws_size;
    const float* k  = (const float*)d_in[0];
    const float* q  = (const float*)d_in[1];
    const float* v  = (const float*)d_in[2];
    const float* Wk = (const float*)d_in[3];
    const float* Wq = (const float*)d_in[4];
    const float* Wv = (const float*)d_in[5];

    ushort* wsu = (ushort*)d_ws;
    const size_t PROJ_ELEMS = (size_t)B_ * T_ * H_;        // 2,097,152
    ushort* kp  = wsu;
    ushort* qp  = wsu + PROJ_ELEMS;
    ushort* vpt = wsu + 2 * PROJ_ELEMS;
    ushort* Wt  = wsu + 3 * PROJ_ELEMS;                    // 393,216 ushorts
    char*  fbase = (char*)d_ws + (3 * PROJ_ELEMS + 393216) * sizeof(ushort);
    float* Mpart = (float*)fbase;                          // S_*B*T floats
    float* Lpart = Mpart + (size_t)S_ * B_ * T_;
    ushort* Opart = (ushort*)(Lpart + (size_t)S_ * B_ * T_);  // S_*B*T*H bf16

    prep_w_kernel<<<dim3((E_ * H_ + 255) / 256, 3), 256, 0, stream>>>(Wk, Wq, Wv, Wt);
    proj_kernel<<<dim3((B_ * T_) / 128, 3), 256, 0, stream>>>(k, q, v, Wt, kp, qp, vpt);
    attn_kernel<<<dim3(S_, T_ / 128, B_), 256, 0, stream>>>(kp, qp, vpt, Opart, Mpart, Lpart);
    combine_kernel<<<dim3(B_ * T_ / 2), 256, 0, stream>>>(Opart, Mpart, Lpart, (float*)d_out);
}

// Round 3
// 303.883 us; speedup vs baseline: 1.1946x; 1.0769x over previous
//
#include <hip/hip_runtime.h>
#include <math.h>

#define B_ 4
#define T_ 4096
#define E_ 1024
#define H_ 128
#define S_ 8          // attention split-K factor

typedef __attribute__((ext_vector_type(8))) short short8;
typedef __attribute__((ext_vector_type(4))) float f32x4;
typedef unsigned short ushort;

__device__ __forceinline__ ushort f2bf(float f) {          // RNE
    union { float f; unsigned int u; } v; v.f = f;
    unsigned int r = v.u + 0x7fffu + ((v.u >> 16) & 1u);
    return (ushort)(r >> 16);
}
__device__ __forceinline__ float bf2f(ushort u) {
    union { unsigned int u; float f; } v; v.u = ((unsigned int)u) << 16;
    return v.f;
}
__device__ __forceinline__ unsigned int pkbf(float hi, float lo) { // [bf16(hi)|bf16(lo)] truncated
    return __builtin_amdgcn_perm(__float_as_uint(hi), __float_as_uint(lo), 0x07060302u);
}

typedef __attribute__((address_space(3))) unsigned int lds_u32;
typedef __attribute__((address_space(1))) const unsigned int g_u32;
__device__ __forceinline__ void gload16(const void* g, void* l) {
    __builtin_amdgcn_global_load_lds((g_u32*)g, (lds_u32*)l, 16, 0, 0);
}

// ---------------------------------------------------------------------------
// Kernel 1: W[E][H] fp32 -> Wt[H][E] bf16
// ---------------------------------------------------------------------------
__global__ void prep_w_kernel(const float* __restrict__ Wk,
                              const float* __restrict__ Wq,
                              const float* __restrict__ Wv,
                              ushort* __restrict__ Wt) {
    int sel = blockIdx.y;
    const float* W = (sel == 0) ? Wk : ((sel == 1) ? Wq : Wv);
    ushort* out = Wt + (size_t)sel * (E_ * H_);
    int idx = blockIdx.x * blockDim.x + threadIdx.x;
    if (idx < E_ * H_) {
        int e = idx >> 7;
        int h = idx & (H_ - 1);
        out[(size_t)h * E_ + e] = f2bf(W[idx]);
    }
}

// ---------------------------------------------------------------------------
// Kernel 2: projection GEMM, M-tile 64 (16 rows/wave), BK=64, grid 768
// X staged raw fp32 via global_load_lds, converted on A-frag read (v_perm)
// ---------------------------------------------------------------------------
__launch_bounds__(256, 3)
__global__ void proj_kernel(const float* __restrict__ Xk,
                            const float* __restrict__ Xq,
                            const float* __restrict__ Xv,
                            const ushort* __restrict__ Wt,
                            ushort* __restrict__ kp,
                            ushort* __restrict__ qp,
                            ushort* __restrict__ vpt) {
    int sel = blockIdx.y;
    const float* X = (sel == 0) ? Xk : ((sel == 1) ? Xq : Xv);
    const ushort* W = Wt + (size_t)sel * (E_ * H_);

    __shared__ __align__(16) unsigned char psm[32768];
    float*  Xs = (float*)psm;              // [64 rows][64 f32], pair-swizzled chunks
    ushort* Ws = (ushort*)(psm + 16384);   // [128 n][64 k] bf16, swizzled 8 chunks/row
    ushort* Ot = (ushort*)psm;             // epilogue alias [128 h][72]

    int t = threadIdx.x;
    int wave = t >> 6, lane = t & 63;
    int l15 = lane & 15, quad = lane >> 4;
    int m0 = blockIdx.x * 64;

    auto stage = [&](int k0) {
        // X: 64 rows x 16 chunks(16B), pair-granular XOR swizzle
#pragma unroll
        for (int i = 0; i < 4; i++) {
            int slot = i * 256 + t;
            int row = slot >> 4, jst = slot & 15;
            int pp = (jst >> 1) ^ (row & 7);
            int jsrc = pp * 2 + (jst & 1);
            gload16(X + (size_t)(m0 + row) * E_ + k0 + jsrc * 4, &Xs[slot * 4]);
        }
        // W: 128 rows x 8 chunks(16B), XOR swizzle
#pragma unroll
        for (int i = 0; i < 4; i++) {
            int slot = i * 256 + t;
            int row = slot >> 3, jst = slot & 7;
            int jsrc = jst ^ (row & 7);
            gload16(W + (size_t)row * E_ + k0 + jsrc * 8, &Ws[slot * 8]);
        }
    };

    f32x4 acc[8];
#pragma unroll
    for (int nt = 0; nt < 8; nt++)
#pragma unroll
        for (int j = 0; j < 4; j++) acc[nt][j] = 0.0f;

    stage(0);
    for (int k0 = 0; k0 < E_; k0 += 64) {
        __syncthreads();     // drains gload vmcnt, prev compute done
#pragma unroll
        for (int ks = 0; ks < 2; ks++) {
            int ppr = (ks * 4 + quad) ^ (l15 & 7);
            const float* xb = &Xs[(wave * 16 + l15) * 64 + ppr * 8];
            f32x4 x0 = *(const f32x4*)xb;
            f32x4 x1 = *(const f32x4*)(xb + 4);
            unsigned int aw[4];
            aw[0] = pkbf(x0[1], x0[0]); aw[1] = pkbf(x0[3], x0[2]);
            aw[2] = pkbf(x1[1], x1[0]); aw[3] = pkbf(x1[3], x1[2]);
            short8 a;
            { union { unsigned int w[4]; short8 s; } u; u.w[0]=aw[0]; u.w[1]=aw[1]; u.w[2]=aw[2]; u.w[3]=aw[3]; a = u.s; }
#pragma unroll
            for (int nt = 0; nt < 8; nt++) {
                int n = nt * 16 + l15;
                int jj = (ks * 4 + quad) ^ (n & 7);
                short8 b = *(const short8*)&Ws[n * 64 + jj * 8];
                acc[nt] = __builtin_amdgcn_mfma_f32_16x16x32_bf16(a, b, acc[nt], 0, 0, 0);
            }
        }
        __syncthreads();
        if (k0 + 64 < E_) stage(k0 + 64);
    }

    if (sel < 2) {
        float scale = (sel == 1) ? 0.08838834764831845f : 1.0f;
        ushort* out = (sel == 0) ? kp : qp;
#pragma unroll
        for (int nt = 0; nt < 8; nt++)
#pragma unroll
            for (int r = 0; r < 4; r++) {
                int row = m0 + wave * 16 + quad * 4 + r;
                out[(size_t)row * H_ + nt * 16 + l15] = f2bf(acc[nt][r] * scale);
            }
    } else {
        // transpose to [h][t] via LDS, then b128 coalesced stores
#pragma unroll
        for (int nt = 0; nt < 8; nt++) {
            unsigned int p0 = ((unsigned int)f2bf(acc[nt][0])) | ((unsigned int)f2bf(acc[nt][1]) << 16);
            unsigned int p1 = ((unsigned int)f2bf(acc[nt][2])) | ((unsigned int)f2bf(acc[nt][3]) << 16);
            *(uint2*)&Ot[(nt * 16 + l15) * 72 + wave * 16 + quad * 4] = make_uint2(p0, p1);
        }
        __syncthreads();
        int b = m0 >> 12;
        int t0 = m0 & (T_ - 1);
        int h = t >> 1, half = (t & 1) * 32;
        ushort* dst = vpt + (size_t)b * H_ * T_ + (size_t)h * T_ + t0 + half;
        const ushort* src = &Ot[h * 72 + half];
#pragma unroll
        for (int j = 0; j < 4; j++)
            *(uint4*)(dst + j * 8) = *(const uint4*)(src + j * 8);
    }
}

// ---------------------------------------------------------------------------
// Kernel 3: flash attention partials, S^T formulation, split-K S_=8
// Q-tile 128 (32 q/wave), K-tile 64.  S^T = K Q^T;  O^T = V^T P^T.
// ---------------------------------------------------------------------------
__launch_bounds__(256, 3)
__global__ void attn_kernel(const ushort* __restrict__ kp,
                            const ushort* __restrict__ qp,
                            const ushort* __restrict__ vpt,
                            ushort* __restrict__ Opart,
                            float* __restrict__ Mpart,
                            float* __restrict__ Lpart) {
    __shared__ __align__(16) ushort smem[25600];   // 50 KB
    ushort* Ks = smem;            // [64 key][128 h]  swizzled 16 chunks/row
    ushort* Vs = smem + 8192;     // [128 h][64 key]  swizzled 8 chunks/row
    ushort* Ps = smem + 16384;    // per-wave P^T scratch [32 q][72], 4 waves
    ushort* Ot = smem;            // epilogue alias [128 q][136]

    int t = threadIdx.x;
    int wave = t >> 6, lane = t & 63;
    int l15 = lane & 15, quad = lane >> 4;
    int s = blockIdx.x;
    int qt = blockIdx.y;
    int b = blockIdx.z;
    int q0 = qt * 128;
    int nkt = 2 * qt + 2;

    const ushort* kbase = kp + (size_t)b * T_ * H_;
    const ushort* vbase = vpt + (size_t)b * H_ * T_;

    // Q as B-operand: B[n=query(l15)][k=h(quad*8+j)], queries wave*32+nt*16+l15
    short8 qf[2][4];
#pragma unroll
    for (int nt = 0; nt < 2; nt++)
#pragma unroll
        for (int ks = 0; ks < 4; ks++)
            qf[nt][ks] = *(const short8*)(qp + ((size_t)(b * T_ + q0 + wave * 32 + nt * 16 + l15)) * H_
                                             + ks * 32 + quad * 8);

    f32x4 acc_o[8][2];   // O^T: [h=mtH*16+quad*4+r][query=nt*16+l15]
#pragma unroll
    for (int ht = 0; ht < 8; ht++)
#pragma unroll
        for (int nt = 0; nt < 2; nt++)
#pragma unroll
            for (int j = 0; j < 4; j++) acc_o[ht][nt][j] = 0.0f;
    float m_i[2] = {-INFINITY, -INFINITY}, l_i[2] = {0.0f, 0.0f};

    ushort* Psw = Ps + wave * 2304;   // 32*72

    for (int kt = s; kt < nkt; kt += S_) {
        int k0 = kt * 64;
        // stage K [64][128] and V^T [128][64]
#pragma unroll
        for (int i = 0; i < 4; i++) {
            int slot = i * 256 + t;
            int row = slot >> 4, jst = slot & 15;
            int jsrc = jst ^ (row & 15);
            gload16(kbase + (size_t)(k0 + row) * H_ + jsrc * 8, &Ks[slot * 8]);
        }
#pragma unroll
        for (int i = 0; i < 4; i++) {
            int slot = i * 256 + t;
            int row = slot >> 3, jst = slot & 7;
            int jsrc = jst ^ (row & 7);
            gload16(vbase + (size_t)row * T_ + k0 + jsrc * 8, &Vs[slot * 8]);
        }
        __syncthreads();

        // S^T = K Q^T : sc[mt][nt], key = mt*16+quad*4+r, query = nt*16+l15
        f32x4 sc[4][2];
#pragma unroll
        for (int mt = 0; mt < 4; mt++)
#pragma unroll
            for (int nt = 0; nt < 2; nt++)
#pragma unroll
                for (int j = 0; j < 4; j++) sc[mt][nt][j] = 0.0f;
#pragma unroll
        for (int ks = 0; ks < 4; ks++) {
#pragma unroll
            for (int mt = 0; mt < 4; mt++) {
                int jj = (ks * 4 + quad) ^ l15;
                short8 af = *(const short8*)&Ks[(mt * 16 + l15) * 128 + jj * 8];
                sc[mt][0] = __builtin_amdgcn_mfma_f32_16x16x32_bf16(af, qf[0][ks], sc[mt][0], 0, 0, 0);
                sc[mt][1] = __builtin_amdgcn_mfma_f32_16x16x32_bf16(af, qf[1][ks], sc[mt][1], 0, 0, 0);
            }
        }

        // causal mask: key > query -> -inf
        if (k0 + 63 > q0 + wave * 32) {
#pragma unroll
            for (int mt = 0; mt < 4; mt++)
#pragma unroll
                for (int nt = 0; nt < 2; nt++) {
                    int qg = q0 + wave * 32 + nt * 16 + l15;
#pragma unroll
                    for (int r = 0; r < 4; r++) {
                        int kg = k0 + mt * 16 + quad * 4 + r;
                        if (kg > qg) sc[mt][nt][r] = -INFINITY;
                    }
                }
        }

        // online softmax per query column (in-lane tree + 2 cross-quad shuffles)
        float alpha[2];
#pragma unroll
        for (int nt = 0; nt < 2; nt++) {
            float c0 = fmaxf(fmaxf(sc[0][nt][0], sc[0][nt][1]), fmaxf(sc[0][nt][2], sc[0][nt][3]));
            float c1 = fmaxf(fmaxf(sc[1][nt][0], sc[1][nt][1]), fmaxf(sc[1][nt][2], sc[1][nt][3]));
            float c2 = fmaxf(fmaxf(sc[2][nt][0], sc[2][nt][1]), fmaxf(sc[2][nt][2], sc[2][nt][3]));
            float c3 = fmaxf(fmaxf(sc[3][nt][0], sc[3][nt][1]), fmaxf(sc[3][nt][2], sc[3][nt][3]));
            float cmax = fmaxf(fmaxf(c0, c1), fmaxf(c2, c3));
            cmax = fmaxf(cmax, __shfl_xor(cmax, 16));
            cmax = fmaxf(cmax, __shfl_xor(cmax, 32));
            float mnew = fmaxf(m_i[nt], cmax);
            float msafe = fmaxf(mnew, -1e30f);
            alpha[nt] = __expf(m_i[nt] - msafe);
            m_i[nt] = mnew;
            float rs = 0.0f;
#pragma unroll
            for (int mt = 0; mt < 4; mt++) {
                float p0 = __expf(sc[mt][nt][0] - msafe);
                float p1 = __expf(sc[mt][nt][1] - msafe);
                float p2 = __expf(sc[mt][nt][2] - msafe);
                float p3 = __expf(sc[mt][nt][3] - msafe);
                sc[mt][nt][0] = p0; sc[mt][nt][1] = p1; sc[mt][nt][2] = p2; sc[mt][nt][3] = p3;
                rs += (p0 + p1) + (p2 + p3);
            }
            rs += __shfl_xor(rs, 16);
            rs += __shfl_xor(rs, 32);
            l_i[nt] = l_i[nt] * alpha[nt] + rs;
        }

        // write P^T to own-wave LDS: [query 32][key 64] stride 72, packed b64
#pragma unroll
        for (int mt = 0; mt < 4; mt++)
#pragma unroll
            for (int nt = 0; nt < 2; nt++) {
                uint2 w = make_uint2(pkbf(sc[mt][nt][1], sc[mt][nt][0]),
                                     pkbf(sc[mt][nt][3], sc[mt][nt][2]));
                *(uint2*)&Psw[(nt * 16 + l15) * 72 + mt * 16 + quad * 4] = w;
            }

        // rescale O
#pragma unroll
        for (int ht = 0; ht < 8; ht++)
#pragma unroll
            for (int nt = 0; nt < 2; nt++)
#pragma unroll
                for (int r = 0; r < 4; r++) acc_o[ht][nt][r] *= alpha[nt];

        // O^T += V^T P^T
#pragma unroll
        for (int ks2 = 0; ks2 < 2; ks2++) {
            short8 pb[2];
#pragma unroll
            for (int nt = 0; nt < 2; nt++)
                pb[nt] = *(const short8*)&Psw[(nt * 16 + l15) * 72 + ks2 * 32 + quad * 8];
#pragma unroll
            for (int ht = 0; ht < 8; ht++) {
                int jj = (ks2 * 4 + quad) ^ (l15 & 7);
                short8 af = *(const short8*)&Vs[(ht * 16 + l15) * 64 + jj * 8];
                acc_o[ht][0] = __builtin_amdgcn_mfma_f32_16x16x32_bf16(af, pb[0], acc_o[ht][0], 0, 0, 0);
                acc_o[ht][1] = __builtin_amdgcn_mfma_f32_16x16x32_bf16(af, pb[1], acc_o[ht][1], 0, 0, 0);
            }
        }
        __syncthreads();
    }

    // epilogue: transpose O^T -> [query][h] via LDS, b128 partial stores
    const size_t BT = (size_t)B_ * T_;
#pragma unroll
    for (int nt = 0; nt < 2; nt++) {
        if (quad == 0) {
            int grow = b * T_ + q0 + wave * 32 + nt * 16 + l15;
            Mpart[(size_t)s * BT + grow] = m_i[nt];
            Lpart[(size_t)s * BT + grow] = l_i[nt];
        }
    }
#pragma unroll
    for (int ht = 0; ht < 8; ht++)
#pragma unroll
        for (int nt = 0; nt < 2; nt++) {
            uint2 w = make_uint2(((unsigned int)f2bf(acc_o[ht][nt][0])) | ((unsigned int)f2bf(acc_o[ht][nt][1]) << 16),
                                 ((unsigned int)f2bf(acc_o[ht][nt][2])) | ((unsigned int)f2bf(acc_o[ht][nt][3]) << 16));
            *(uint2*)&Ot[(wave * 32 + nt * 16 + l15) * 136 + ht * 16 + quad * 4] = w;
        }
    __syncthreads();
    {
        int query = t >> 1, half = (t & 1) * 64;
        size_t row = (size_t)s * BT + b * T_ + q0 + query;
        ushort* dst = Opart + row * H_ + half;
        const ushort* src = &Ot[query * 136 + half];
#pragma unroll
        for (int j = 0; j < 8; j++)
            *(uint4*)(dst + j * 8) = *(const uint4*)(src + j * 8);
    }
}

// ---------------------------------------------------------------------------
// Kernel 4: combine split-K partials
// ---------------------------------------------------------------------------
__launch_bounds__(256)
__global__ void combine_kernel(const ushort* __restrict__ Opart,
                               const float* __restrict__ Mpart,
                               const float* __restrict__ Lpart,
                               float* __restrict__ out) {
    int t = threadIdx.x;
    int row = blockIdx.x * 2 + (t >> 7);
    int col = t & 127;
    const size_t BT = (size_t)B_ * T_;
    float m[S_], l[S_];
#pragma unroll
    for (int s = 0; s < S_; s++) {
        m[s] = Mpart[(size_t)s * BT + row];
        l[s] = Lpart[(size_t)s * BT + row];
    }
    float M = m[0];
#pragma unroll
    for (int s = 1; s < S_; s++) M = fmaxf(M, m[s]);
    float den = 0.0f, acc = 0.0f;
#pragma unroll
    for (int s = 0; s < S_; s++) {
        float w = __expf(m[s] - M);
        den += l[s] * w;
        acc += w * bf2f(Opart[((size_t)s * BT + row) * H_ + col]);
    }
    out[(size_t)row * H_ + col] = acc / den;
}

// ---------------------------------------------------------------------------
extern "C" void kernel_launch(void* const* d_in, const int* in_sizes, int n_in,
                              void* d_out, int out_size, void* d_ws, size_t ws_size,
                              hipStream_t stream) {
    (void)in_sizes; (void)n_in; (void)out_size; (void)ws_size;
    const float* k  = (const float*)d_in[0];
    const float* q  = (const float*)d_in[1];
    const float* v  = (const float*)d_in[2];
    const float* Wk = (const float*)d_in[3];
    const float* Wq = (const float*)d_in[4];
    const float* Wv = (const float*)d_in[5];

    ushort* wsu = (ushort*)d_ws;
    const size_t PROJ_ELEMS = (size_t)B_ * T_ * H_;        // 2,097,152
    ushort* kp  = wsu;
    ushort* qp  = wsu + PROJ_ELEMS;
    ushort* vpt = wsu + 2 * PROJ_ELEMS;
    ushort* Wt  = wsu + 3 * PROJ_ELEMS;                    // 393,216 ushorts
    char*  fbase = (char*)d_ws + (3 * PROJ_ELEMS + 393216) * sizeof(ushort);
    float* Mpart = (float*)fbase;                          // S_*B*T floats
    float* Lpart = Mpart + (size_t)S_ * B_ * T_;
    ushort* Opart = (ushort*)(Lpart + (size_t)S_ * B_ * T_);  // S_*B*T*H bf16

    prep_w_kernel<<<dim3((E_ * H_ + 255) / 256, 3), 256, 0, stream>>>(Wk, Wq, Wv, Wt);
    proj_kernel<<<dim3((B_ * T_) / 64, 3), 256, 0, stream>>>(k, q, v, Wt, kp, qp, vpt);
    attn_kernel<<<dim3(S_, T_ / 128, B_), 256, 0, stream>>>(kp, qp, vpt, Opart, Mpart, Lpart);
    combine_kernel<<<dim3(B_ * T_ / 2), 256, 0, stream>>>(Opart, Mpart, Lpart, (float*)d_out);
}

// Round 4
// 269.061 us; speedup vs baseline: 1.3492x; 1.1294x over previous
//
#include <hip/hip_runtime.h>
#include <math.h>

#define B_ 4
#define T_ 4096
#define E_ 1024
#define H_ 128
#define S_ 8          // attention split-K factor

typedef __attribute__((ext_vector_type(8))) short short8;
typedef __attribute__((ext_vector_type(4))) float f32x4;
typedef __attribute__((ext_vector_type(16))) float f32x16;
typedef unsigned short ushort;

__device__ __forceinline__ ushort f2bf(float f) {          // RNE
    union { float f; unsigned int u; } v; v.f = f;
    unsigned int r = v.u + 0x7fffu + ((v.u >> 16) & 1u);
    return (ushort)(r >> 16);
}
__device__ __forceinline__ float bf2f(ushort u) {
    union { unsigned int u; float f; } v; v.u = ((unsigned int)u) << 16;
    return v.f;
}
__device__ __forceinline__ unsigned int pkbf(float hi, float lo) { // [bf16(hi)|bf16(lo)] truncated
    return __builtin_amdgcn_perm(__float_as_uint(hi), __float_as_uint(lo), 0x07060302u);
}

typedef __attribute__((address_space(3))) unsigned int lds_u32;
typedef __attribute__((address_space(1))) const unsigned int g_u32;
__device__ __forceinline__ void gload16(const void* g, void* l) {
    __builtin_amdgcn_global_load_lds((g_u32*)g, (lds_u32*)l, 16, 0, 0);
}

// ---------------------------------------------------------------------------
// Kernel 1: W[E][H] fp32 -> Wt[H][E] bf16
// ---------------------------------------------------------------------------
__global__ void prep_w_kernel(const float* __restrict__ Wk,
                              const float* __restrict__ Wq,
                              const float* __restrict__ Wv,
                              ushort* __restrict__ Wt) {
    int sel = blockIdx.y;
    const float* W = (sel == 0) ? Wk : ((sel == 1) ? Wq : Wv);
    ushort* out = Wt + (size_t)sel * (E_ * H_);
    int idx = blockIdx.x * blockDim.x + threadIdx.x;
    if (idx < E_ * H_) {
        int e = idx >> 7;
        int h = idx & (H_ - 1);
        out[(size_t)h * E_ + e] = f2bf(W[idx]);
    }
}

// ---------------------------------------------------------------------------
// Kernel 2: projection GEMM, M-tile 64 (16 rows/wave), BK=64
// X in registers (prefetched 1 iter ahead); W in double-buffered LDS via
// global_load_lds. Pipelined: barrier -> stage(next,alt) -> compute(cur).
// ---------------------------------------------------------------------------
__launch_bounds__(256, 3)
__global__ void proj_kernel(const float* __restrict__ Xk,
                            const float* __restrict__ Xq,
                            const float* __restrict__ Xv,
                            const ushort* __restrict__ Wt,
                            ushort* __restrict__ kp,
                            ushort* __restrict__ qp,
                            ushort* __restrict__ vpt) {
    int sel = blockIdx.y;
    const float* X = (sel == 0) ? Xk : ((sel == 1) ? Xq : Xv);
    const ushort* W = Wt + (size_t)sel * (E_ * H_);

    __shared__ __align__(16) ushort smem[16384];   // 32 KB: Ws dbuf 2 x 8192
    ushort* Ot = smem;                             // epilogue alias [128 h][72]

    int t = threadIdx.x;
    int wave = t >> 6, lane = t & 63;
    int l15 = lane & 15, quad = lane >> 4;
    int m0 = blockIdx.x * 64;

    auto stageW = [&](int k0, ushort* buf) {
#pragma unroll
        for (int i = 0; i < 4; i++) {
            int slot = i * 256 + t;
            int row = slot >> 3, jst = slot & 7;
            int jsrc = jst ^ (row & 7);
            gload16(W + (size_t)row * E_ + k0 + jsrc * 8, &buf[slot * 8]);
        }
    };

    const float* xptr = X + (size_t)(m0 + wave * 16 + l15) * E_;
    float4 xa, xb, xc, xd;
    auto loadX = [&](int k0, float4& a, float4& b, float4& c, float4& d) {
        a = *(const float4*)(xptr + k0 + quad * 8);
        b = *(const float4*)(xptr + k0 + quad * 8 + 4);
        c = *(const float4*)(xptr + k0 + 32 + quad * 8);
        d = *(const float4*)(xptr + k0 + 32 + quad * 8 + 4);
    };

    f32x4 acc[8];
#pragma unroll
    for (int nt = 0; nt < 8; nt++)
#pragma unroll
        for (int j = 0; j < 4; j++) acc[nt][j] = 0.0f;

    stageW(0, smem);
    loadX(0, xa, xb, xc, xd);

    for (int k0 = 0; k0 < E_; k0 += 64) {
        __syncthreads();                   // cur buf ready (staged last iter)
        ushort* Wcur = (k0 & 64) ? (smem + 8192) : smem;
        ushort* Walt = (k0 & 64) ? smem : (smem + 8192);
        bool more = (k0 + 64 < E_);
        float4 na, nb, nc, nd;
        if (more) {
            stageW(k0 + 64, Walt);         // in flight during compute below
            loadX(k0 + 64, na, nb, nc, nd);
        }
#pragma unroll
        for (int ks = 0; ks < 2; ks++) {
            const float4& u  = ks ? xc : xa;
            const float4& v2 = ks ? xd : xb;
            union { unsigned int w[4]; short8 s8; } au;
            au.w[0] = pkbf(u.y, u.x);  au.w[1] = pkbf(u.w, u.z);
            au.w[2] = pkbf(v2.y, v2.x); au.w[3] = pkbf(v2.w, v2.z);
#pragma unroll
            for (int nt = 0; nt < 8; nt++) {
                int n = nt * 16 + l15;
                int jj = (ks * 4 + quad) ^ (n & 7);
                short8 b = *(const short8*)&Wcur[n * 64 + jj * 8];
                acc[nt] = __builtin_amdgcn_mfma_f32_16x16x32_bf16(au.s8, b, acc[nt], 0, 0, 0);
            }
        }
        if (more) { xa = na; xb = nb; xc = nc; xd = nd; }
    }

    if (sel < 2) {
        float scale = (sel == 1) ? 0.08838834764831845f : 1.0f;
        ushort* out = (sel == 0) ? kp : qp;
#pragma unroll
        for (int nt = 0; nt < 8; nt++)
#pragma unroll
            for (int r = 0; r < 4; r++) {
                int row = m0 + wave * 16 + quad * 4 + r;
                out[(size_t)row * H_ + nt * 16 + l15] = f2bf(acc[nt][r] * scale);
            }
    } else {
        __syncthreads();                   // done with Ws before aliasing
#pragma unroll
        for (int nt = 0; nt < 8; nt++) {
            unsigned int p0 = ((unsigned int)f2bf(acc[nt][0])) | ((unsigned int)f2bf(acc[nt][1]) << 16);
            unsigned int p1 = ((unsigned int)f2bf(acc[nt][2])) | ((unsigned int)f2bf(acc[nt][3]) << 16);
            *(uint2*)&Ot[(nt * 16 + l15) * 72 + wave * 16 + quad * 4] = make_uint2(p0, p1);
        }
        __syncthreads();
        int b = m0 >> 12;
        int t0 = m0 & (T_ - 1);
        int h = t >> 1, half = (t & 1) * 32;
        ushort* dst = vpt + (size_t)b * H_ * T_ + (size_t)h * T_ + t0 + half;
        const ushort* src = &Ot[h * 72 + half];
#pragma unroll
        for (int j = 0; j < 4; j++)
            *(uint4*)(dst + j * 8) = *(const uint4*)(src + j * 8);
    }
}

// ---------------------------------------------------------------------------
// Kernel 3: flash attention partials, 32x32x16 MFMA, split-K S_=8
// Wave = 32 queries; S^T = K Q^T; O^T = V^T P^T (P via shfl_xor(32), no LDS P)
// K/V double-buffered via global_load_lds; single barrier per iter.
// ---------------------------------------------------------------------------
__launch_bounds__(256, 2)
__global__ void attn_kernel(const ushort* __restrict__ kp,
                            const ushort* __restrict__ qp,
                            const ushort* __restrict__ vpt,
                            ushort* __restrict__ Opart,
                            float* __restrict__ Mpart,
                            float* __restrict__ Lpart) {
    __shared__ __align__(16) ushort smem[32768];   // 64 KB: 2 x (Ks 8192 + Vs 8192)
    int t = threadIdx.x;
    int wave = t >> 6, lane = t & 63;
    int l31 = lane & 31, h = lane >> 5;
    int s = blockIdx.x, qt = blockIdx.y, b = blockIdx.z;
    int q0 = qt * 128;
    int nkt = 2 * qt + 2;
    int query = q0 + wave * 32 + l31;

    const ushort* kbase = kp + (size_t)b * T_ * H_;
    const ushort* vbase = vpt + (size_t)b * H_ * T_;

    // Q as B-operand (32x32x16): B[n=query=lane&31][k=h=(lane>>5)*8+j], 8 steps
    short8 qf[8];
#pragma unroll
    for (int kh = 0; kh < 8; kh++)
        qf[kh] = *(const short8*)(qp + ((size_t)b * T_ + query) * H_ + kh * 16 + h * 8);

    f32x16 ao[4];                         // O^T acc: [hc][reg], col = query
#pragma unroll
    for (int hc = 0; hc < 4; hc++)
#pragma unroll
        for (int j = 0; j < 16; j++) ao[hc][j] = 0.0f;
    float m_i = -INFINITY, l_i = 0.0f;

    auto stage = [&](int kt, int buf) {
        ushort* Ksb = smem + buf * 16384;
        ushort* Vsb = Ksb + 8192;
        int k0 = kt * 64;
#pragma unroll
        for (int i = 0; i < 4; i++) {
            int slot = i * 256 + t;
            int row = slot >> 4, jst = slot & 15;
            int jsrc = jst ^ (row & 15);
            gload16(kbase + (size_t)(k0 + row) * H_ + jsrc * 8, &Ksb[slot * 8]);
        }
#pragma unroll
        for (int i = 0; i < 4; i++) {
            int slot = i * 256 + t;
            int row = slot >> 3, jst = slot & 7;
            int jsrc = jst ^ (row & 7);
            gload16(vbase + (size_t)row * T_ + k0 + jsrc * 8, &Vsb[slot * 8]);
        }
    };

    int cur = 0;
    if (s < nkt) stage(s, 0);

    for (int kt = s; kt < nkt; kt += S_) {
        __syncthreads();                   // cur buffers ready
        if (kt + S_ < nkt) stage(kt + S_, cur ^ 1);
        const ushort* Ksb = smem + cur * 16384;
        const ushort* Vsb = Ksb + 8192;
        int k0 = kt * 64;

        // S^T = K Q^T : s0 = keys 0..31, s1 = keys 32..63; col = query
        f32x16 s0, s1;
#pragma unroll
        for (int j = 0; j < 16; j++) { s0[j] = 0.0f; s1[j] = 0.0f; }
#pragma unroll
        for (int kh = 0; kh < 8; kh++) {
            int slot = (kh * 2 + h) ^ (l31 & 15);
            short8 a0 = *(const short8*)&Ksb[l31 * 128 + slot * 8];
            short8 a1 = *(const short8*)&Ksb[(32 + l31) * 128 + slot * 8];
            s0 = __builtin_amdgcn_mfma_f32_32x32x16_bf16(a0, qf[kh], s0, 0, 0, 0);
            s1 = __builtin_amdgcn_mfma_f32_32x32x16_bf16(a1, qf[kh], s1, 0, 0, 0);
        }

        // causal mask: key row = (r&3)+8*(r>>2)+4h (+32 for s1)
        if (k0 + 63 > q0 + wave * 32) {
#pragma unroll
            for (int rq = 0; rq < 4; rq++)
#pragma unroll
                for (int rr = 0; rr < 4; rr++) {
                    int koff = rr + rq * 8 + h * 4;
                    if (k0 + koff > query)      s0[rq * 4 + rr] = -INFINITY;
                    if (k0 + 32 + koff > query) s1[rq * 4 + rr] = -INFINITY;
                }
        }

        // online softmax per query (in-lane over 32 + one shfl_xor(32))
        float cmax = -INFINITY;
#pragma unroll
        for (int j = 0; j < 16; j++) cmax = fmaxf(cmax, fmaxf(s0[j], s1[j]));
        cmax = fmaxf(cmax, __shfl_xor(cmax, 32));
        float mnew = fmaxf(m_i, cmax);
        float msafe = fmaxf(mnew, -1e30f);
        float alpha = __expf(m_i - msafe);
        m_i = mnew;
        float rs = 0.0f;
#pragma unroll
        for (int j = 0; j < 16; j++) {
            s0[j] = __expf(s0[j] - msafe);
            s1[j] = __expf(s1[j] - msafe);
            rs += s0[j] + s1[j];
        }
        rs += __shfl_xor(rs, 32);
        l_i = l_i * alpha + rs;
#pragma unroll
        for (int hc = 0; hc < 4; hc++)
#pragma unroll
            for (int j = 0; j < 16; j++) ao[hc][j] *= alpha;

        // O^T += V^T P^T ; P^T B-frag built via shfl_xor(32) from S^T C-frags
#pragma unroll
        for (int kk = 0; kk < 4; kk++) {
            const f32x16& sf = (kk < 2) ? s0 : s1;
            int base = (kk & 1) * 8;
            unsigned int q0x = pkbf(sf[base + 1], sf[base + 0]);
            unsigned int q0y = pkbf(sf[base + 3], sf[base + 2]);
            unsigned int q1x = pkbf(sf[base + 5], sf[base + 4]);
            unsigned int q1y = pkbf(sf[base + 7], sf[base + 6]);
            unsigned int t0x = __shfl_xor(q0x, 32);
            unsigned int t0y = __shfl_xor(q0y, 32);
            unsigned int t1x = __shfl_xor(q1x, 32);
            unsigned int t1y = __shfl_xor(q1y, 32);
            union { unsigned int w[4]; short8 s8; } bu;
            bu.w[0] = h ? t1x : q0x;
            bu.w[1] = h ? t1y : q0y;
            bu.w[2] = h ? q1x : t0x;
            bu.w[3] = h ? q1y : t0y;
#pragma unroll
            for (int hc = 0; hc < 4; hc++) {
                int row = hc * 32 + l31;
                int slot = (kk * 2 + h) ^ (row & 7);
                short8 av = *(const short8*)&Vsb[row * 64 + slot * 8];
                ao[hc] = __builtin_amdgcn_mfma_f32_32x32x16_bf16(av, bu.s8, ao[hc], 0, 0, 0);
            }
        }
        cur ^= 1;
    }

    // epilogue
    const size_t BT = (size_t)B_ * T_;
    __syncthreads();                       // all compute done before aliasing smem
    if (lane < 32) {
        int grow = b * T_ + query;
        Mpart[(size_t)s * BT + grow] = m_i;
        Lpart[(size_t)s * BT + grow] = l_i;
    }
    ushort* Ot = smem;                     // [128 q][136]
#pragma unroll
    for (int hc = 0; hc < 4; hc++)
#pragma unroll
        for (int rq = 0; rq < 4; rq++) {
            uint2 w = make_uint2(
                ((unsigned int)f2bf(ao[hc][rq * 4 + 0])) | ((unsigned int)f2bf(ao[hc][rq * 4 + 1]) << 16),
                ((unsigned int)f2bf(ao[hc][rq * 4 + 2])) | ((unsigned int)f2bf(ao[hc][rq * 4 + 3]) << 16));
            *(uint2*)&Ot[(wave * 32 + l31) * 136 + hc * 32 + rq * 8 + h * 4] = w;
        }
    __syncthreads();
    {
        int qq = t >> 1, half = (t & 1) * 64;
        size_t row = (size_t)s * BT + b * T_ + q0 + qq;
        ushort* dst = Opart + row * H_ + half;
        const ushort* src = &Ot[qq * 136 + half];
#pragma unroll
        for (int j = 0; j < 8; j++)
            *(uint4*)(dst + j * 8) = *(const uint4*)(src + j * 8);
    }
}

// ---------------------------------------------------------------------------
// Kernel 4: combine split-K partials
// ---------------------------------------------------------------------------
__launch_bounds__(256)
__global__ void combine_kernel(const ushort* __restrict__ Opart,
                               const float* __restrict__ Mpart,
                               const float* __restrict__ Lpart,
                               float* __restrict__ out) {
    int t = threadIdx.x;
    int row = blockIdx.x * 2 + (t >> 7);
    int col = t & 127;
    const size_t BT = (size_t)B_ * T_;
    float m[S_], l[S_];
#pragma unroll
    for (int s = 0; s < S_; s++) {
        m[s] = Mpart[(size_t)s * BT + row];
        l[s] = Lpart[(size_t)s * BT + row];
    }
    float M = m[0];
#pragma unroll
    for (int s = 1; s < S_; s++) M = fmaxf(M, m[s]);
    float den = 0.0f, acc = 0.0f;
#pragma unroll
    for (int s = 0; s < S_; s++) {
        float w = __expf(m[s] - M);
        den += l[s] * w;
        acc += w * bf2f(Opart[((size_t)s * BT + row) * H_ + col]);
    }
    out[(size_t)row * H_ + col] = acc / den;
}

// ---------------------------------------------------------------------------
extern "C" void kernel_launch(void* const* d_in, const int* in_sizes, int n_in,
                              void* d_out, int out_size, void* d_ws, size_t ws_size,
                              hipStream_t stream) {
    (void)in_sizes; (void)n_in; (void)out_size; (void)ws_size;
    const float* k  = (const float*)d_in[0];
    const float* q  = (const float*)d_in[1];
    const float* v  = (const float*)d_in[2];
    const float* Wk = (const float*)d_in[3];
    const float* Wq = (const float*)d_in[4];
    const float* Wv = (const float*)d_in[5];

    ushort* wsu = (ushort*)d_ws;
    const size_t PROJ_ELEMS = (size_t)B_ * T_ * H_;        // 2,097,152
    ushort* kp  = wsu;
    ushort* qp  = wsu + PROJ_ELEMS;
    ushort* vpt = wsu + 2 * PROJ_ELEMS;
    ushort* Wt  = wsu + 3 * PROJ_ELEMS;                    // 393,216 ushorts
    char*  fbase = (char*)d_ws + (3 * PROJ_ELEMS + 393216) * sizeof(ushort);
    float* Mpart = (float*)fbase;                          // S_*B*T floats
    float* Lpart = Mpart + (size_t)S_ * B_ * T_;
    ushort* Opart = (ushort*)(Lpart + (size_t)S_ * B_ * T_);  // S_*B*T*H bf16

    prep_w_kernel<<<dim3((E_ * H_ + 255) / 256, 3), 256, 0, stream>>>(Wk, Wq, Wv, Wt);
    proj_kernel<<<dim3((B_ * T_) / 64, 3), 256, 0, stream>>>(k, q, v, Wt, kp, qp, vpt);
    attn_kernel<<<dim3(S_, T_ / 128, B_), 256, 0, stream>>>(kp, qp, vpt, Opart, Mpart, Lpart);
    combine_kernel<<<dim3(B_ * T_ / 2), 256, 0, stream>>>(Opart, Mpart, Lpart, (float*)d_out);
}

// Round 5
// 261.999 us; speedup vs baseline: 1.3855x; 1.0270x over previous
//
#include <hip/hip_runtime.h>
#include <math.h>

#define B_ 4
#define T_ 4096
#define E_ 1024
#define H_ 128
#define S_ 8          // attention split-K factor

typedef __attribute__((ext_vector_type(8))) short short8;
typedef __attribute__((ext_vector_type(4))) float f32x4;
typedef __attribute__((ext_vector_type(16))) float f32x16;
typedef unsigned short ushort;

__device__ __forceinline__ ushort f2bf(float f) {          // RNE
    union { float f; unsigned int u; } v; v.f = f;
    unsigned int r = v.u + 0x7fffu + ((v.u >> 16) & 1u);
    return (ushort)(r >> 16);
}
__device__ __forceinline__ float bf2f(ushort u) {
    union { unsigned int u; float f; } v; v.u = ((unsigned int)u) << 16;
    return v.f;
}
__device__ __forceinline__ unsigned int pkbf(float hi, float lo) { // [bf16(hi)|bf16(lo)] truncated
    return __builtin_amdgcn_perm(__float_as_uint(hi), __float_as_uint(lo), 0x07060302u);
}

typedef __attribute__((address_space(3))) unsigned int lds_u32;
typedef __attribute__((address_space(1))) const unsigned int g_u32;
__device__ __forceinline__ void gload16(const void* g, void* l) {
    __builtin_amdgcn_global_load_lds((g_u32*)g, (lds_u32*)l, 16, 0, 0);
}

// ---------------------------------------------------------------------------
// Kernel 1: W[E][H] fp32 -> Wt[H][E] bf16
// ---------------------------------------------------------------------------
__global__ void prep_w_kernel(const float* __restrict__ Wk,
                              const float* __restrict__ Wq,
                              const float* __restrict__ Wv,
                              ushort* __restrict__ Wt) {
    int sel = blockIdx.y;
    const float* W = (sel == 0) ? Wk : ((sel == 1) ? Wq : Wv);
    ushort* out = Wt + (size_t)sel * (E_ * H_);
    int idx = blockIdx.x * blockDim.x + threadIdx.x;
    if (idx < E_ * H_) {
        int e = idx >> 7;
        int h = idx & (H_ - 1);
        out[(size_t)h * E_ + e] = f2bf(W[idx]);
    }
}

// ---------------------------------------------------------------------------
// Kernel 2: projection GEMM, M-tile 64 (16 rows/wave), BK=64
// X in registers (prefetched 1 iter ahead); W in double-buffered LDS.
// K-loop start STAGGERED per block (channel spread); fp32 acc is order-safe.
// ---------------------------------------------------------------------------
__launch_bounds__(256, 3)
__global__ void proj_kernel(const float* __restrict__ Xk,
                            const float* __restrict__ Xq,
                            const float* __restrict__ Xv,
                            const ushort* __restrict__ Wt,
                            ushort* __restrict__ kp,
                            ushort* __restrict__ qp,
                            ushort* __restrict__ vpt) {
    int sel = blockIdx.y;
    const float* X = (sel == 0) ? Xk : ((sel == 1) ? Xq : Xv);
    const ushort* W = Wt + (size_t)sel * (E_ * H_);

    __shared__ __align__(16) ushort smem[16384];   // 32 KB: Ws dbuf 2 x 8192
    ushort* Ot = smem;                             // epilogue alias [128 h][72]

    int t = threadIdx.x;
    int wave = t >> 6, lane = t & 63;
    int l15 = lane & 15, quad = lane >> 4;
    int m0 = blockIdx.x * 64;
    int koff = (blockIdx.x & 15) * 64;             // per-block k-stagger

    auto stageW = [&](int k0, ushort* buf) {
#pragma unroll
        for (int i = 0; i < 4; i++) {
            int slot = i * 256 + t;
            int row = slot >> 3, jst = slot & 7;
            int jsrc = jst ^ (row & 7);
            gload16(W + (size_t)row * E_ + k0 + jsrc * 8, &buf[slot * 8]);
        }
    };

    const float* xptr = X + (size_t)(m0 + wave * 16 + l15) * E_;
    float4 xa, xb, xc, xd;
    auto loadX = [&](int k0, float4& a, float4& b, float4& c, float4& d) {
        a = *(const float4*)(xptr + k0 + quad * 8);
        b = *(const float4*)(xptr + k0 + quad * 8 + 4);
        c = *(const float4*)(xptr + k0 + 32 + quad * 8);
        d = *(const float4*)(xptr + k0 + 32 + quad * 8 + 4);
    };

    f32x4 acc[8];
#pragma unroll
    for (int nt = 0; nt < 8; nt++)
#pragma unroll
        for (int j = 0; j < 4; j++) acc[nt][j] = 0.0f;

    stageW(koff, smem);
    loadX(koff, xa, xb, xc, xd);

    for (int it = 0; it < 16; it++) {
        __syncthreads();                   // cur buf ready (staged last iter)
        ushort* Wcur = (it & 1) ? (smem + 8192) : smem;
        ushort* Walt = (it & 1) ? smem : (smem + 8192);
        bool more = (it + 1 < 16);
        int knext = (koff + (it + 1) * 64) & (E_ - 1);
        float4 na, nb, nc, nd;
        if (more) {
            stageW(knext, Walt);           // in flight during compute below
            loadX(knext, na, nb, nc, nd);
        }
#pragma unroll
        for (int ks = 0; ks < 2; ks++) {
            const float4& u  = ks ? xc : xa;
            const float4& v2 = ks ? xd : xb;
            union { unsigned int w[4]; short8 s8; } au;
            au.w[0] = pkbf(u.y, u.x);  au.w[1] = pkbf(u.w, u.z);
            au.w[2] = pkbf(v2.y, v2.x); au.w[3] = pkbf(v2.w, v2.z);
#pragma unroll
            for (int nt = 0; nt < 8; nt++) {
                int n = nt * 16 + l15;
                int jj = (ks * 4 + quad) ^ (n & 7);
                short8 b = *(const short8*)&Wcur[n * 64 + jj * 8];
                acc[nt] = __builtin_amdgcn_mfma_f32_16x16x32_bf16(au.s8, b, acc[nt], 0, 0, 0);
            }
        }
        if (more) { xa = na; xb = nb; xc = nc; xd = nd; }
    }

    if (sel < 2) {
        float scale = (sel == 1) ? 0.08838834764831845f : 1.0f;
        ushort* out = (sel == 0) ? kp : qp;
#pragma unroll
        for (int nt = 0; nt < 8; nt++)
#pragma unroll
            for (int r = 0; r < 4; r++) {
                int row = m0 + wave * 16 + quad * 4 + r;
                out[(size_t)row * H_ + nt * 16 + l15] = f2bf(acc[nt][r] * scale);
            }
    } else {
        __syncthreads();                   // done with Ws before aliasing
#pragma unroll
        for (int nt = 0; nt < 8; nt++) {
            unsigned int p0 = ((unsigned int)f2bf(acc[nt][0])) | ((unsigned int)f2bf(acc[nt][1]) << 16);
            unsigned int p1 = ((unsigned int)f2bf(acc[nt][2])) | ((unsigned int)f2bf(acc[nt][3]) << 16);
            *(uint2*)&Ot[(nt * 16 + l15) * 72 + wave * 16 + quad * 4] = make_uint2(p0, p1);
        }
        __syncthreads();
        int b = m0 >> 12;
        int t0 = m0 & (T_ - 1);
        int h = t >> 1, half = (t & 1) * 32;
        ushort* dst = vpt + (size_t)b * H_ * T_ + (size_t)h * T_ + t0 + half;
        const ushort* src = &Ot[h * 72 + half];
#pragma unroll
        for (int j = 0; j < 4; j++)
            *(uint4*)(dst + j * 8) = *(const uint4*)(src + j * 8);
    }
}

// ---------------------------------------------------------------------------
// Kernel 3: flash attention partials, 32x32x16 MFMA, split-K S_=8
// Wave = 32 queries; S^T = K Q^T; O^T = V^T P^T (P via shfl_xor(32), no LDS P)
// K/V double-buffered via global_load_lds; heavy (large-qt) blocks launch 1st.
// ---------------------------------------------------------------------------
__launch_bounds__(256, 2)
__global__ void attn_kernel(const ushort* __restrict__ kp,
                            const ushort* __restrict__ qp,
                            const ushort* __restrict__ vpt,
                            ushort* __restrict__ Opart,
                            float* __restrict__ Mpart,
                            float* __restrict__ Lpart) {
    __shared__ __align__(16) ushort smem[32768];   // 64 KB: 2 x (Ks 8192 + Vs 8192)
    int t = threadIdx.x;
    int wave = t >> 6, lane = t & 63;
    int l31 = lane & 31, h = lane >> 5;
    int s = blockIdx.x;
    int qt = (int)gridDim.y - 1 - (int)blockIdx.y;   // heavy blocks first
    int b = blockIdx.z;
    int q0 = qt * 128;
    int nkt = 2 * qt + 2;
    int query = q0 + wave * 32 + l31;

    const ushort* kbase = kp + (size_t)b * T_ * H_;
    const ushort* vbase = vpt + (size_t)b * H_ * T_;

    // Q as B-operand (32x32x16): B[n=query=lane&31][k=h=(lane>>5)*8+j], 8 steps
    short8 qf[8];
#pragma unroll
    for (int kh = 0; kh < 8; kh++)
        qf[kh] = *(const short8*)(qp + ((size_t)b * T_ + query) * H_ + kh * 16 + h * 8);

    f32x16 ao[4];                         // O^T acc: [hc][reg], col = query
#pragma unroll
    for (int hc = 0; hc < 4; hc++)
#pragma unroll
        for (int j = 0; j < 16; j++) ao[hc][j] = 0.0f;
    float m_i = -INFINITY, l_i = 0.0f;

    auto stage = [&](int kt, int buf) {
        ushort* Ksb = smem + buf * 16384;
        ushort* Vsb = Ksb + 8192;
        int k0 = kt * 64;
#pragma unroll
        for (int i = 0; i < 4; i++) {
            int slot = i * 256 + t;
            int row = slot >> 4, jst = slot & 15;
            int jsrc = jst ^ (row & 15);
            gload16(kbase + (size_t)(k0 + row) * H_ + jsrc * 8, &Ksb[slot * 8]);
        }
#pragma unroll
        for (int i = 0; i < 4; i++) {
            int slot = i * 256 + t;
            int row = slot >> 3, jst = slot & 7;
            int jsrc = jst ^ (row & 7);
            gload16(vbase + (size_t)row * T_ + k0 + jsrc * 8, &Vsb[slot * 8]);
        }
    };

    int cur = 0;
    if (s < nkt) stage(s, 0);

    for (int kt = s; kt < nkt; kt += S_) {
        __syncthreads();                   // cur buffers ready
        if (kt + S_ < nkt) stage(kt + S_, cur ^ 1);
        const ushort* Ksb = smem + cur * 16384;
        const ushort* Vsb = Ksb + 8192;
        int k0 = kt * 64;

        // S^T = K Q^T : s0 = keys 0..31, s1 = keys 32..63; col = query
        f32x16 s0, s1;
#pragma unroll
        for (int j = 0; j < 16; j++) { s0[j] = 0.0f; s1[j] = 0.0f; }
#pragma unroll
        for (int kh = 0; kh < 8; kh++) {
            int slot = (kh * 2 + h) ^ (l31 & 15);
            short8 a0 = *(const short8*)&Ksb[l31 * 128 + slot * 8];
            short8 a1 = *(const short8*)&Ksb[(32 + l31) * 128 + slot * 8];
            s0 = __builtin_amdgcn_mfma_f32_32x32x16_bf16(a0, qf[kh], s0, 0, 0, 0);
            s1 = __builtin_amdgcn_mfma_f32_32x32x16_bf16(a1, qf[kh], s1, 0, 0, 0);
        }

        // causal mask: key row = (r&3)+8*(r>>2)+4h (+32 for s1)
        if (k0 + 63 > q0 + wave * 32) {
#pragma unroll
            for (int rq = 0; rq < 4; rq++)
#pragma unroll
                for (int rr = 0; rr < 4; rr++) {
                    int koff = rr + rq * 8 + h * 4;
                    if (k0 + koff > query)      s0[rq * 4 + rr] = -INFINITY;
                    if (k0 + 32 + koff > query) s1[rq * 4 + rr] = -INFINITY;
                }
        }

        // online softmax per query (in-lane over 32 + one shfl_xor(32))
        float cmax = -INFINITY;
#pragma unroll
        for (int j = 0; j < 16; j++) cmax = fmaxf(cmax, fmaxf(s0[j], s1[j]));
        cmax = fmaxf(cmax, __shfl_xor(cmax, 32));
        float mnew = fmaxf(m_i, cmax);
        float msafe = fmaxf(mnew, -1e30f);
        float alpha = __expf(m_i - msafe);
        m_i = mnew;
        float rs = 0.0f;
#pragma unroll
        for (int j = 0; j < 16; j++) {
            s0[j] = __expf(s0[j] - msafe);
            s1[j] = __expf(s1[j] - msafe);
            rs += s0[j] + s1[j];
        }
        rs += __shfl_xor(rs, 32);
        l_i = l_i * alpha + rs;
#pragma unroll
        for (int hc = 0; hc < 4; hc++)
#pragma unroll
            for (int j = 0; j < 16; j++) ao[hc][j] *= alpha;

        // O^T += V^T P^T ; P^T B-frag built via shfl_xor(32) from S^T C-frags
#pragma unroll
        for (int kk = 0; kk < 4; kk++) {
            const f32x16& sf = (kk < 2) ? s0 : s1;
            int base = (kk & 1) * 8;
            unsigned int q0x = pkbf(sf[base + 1], sf[base + 0]);
            unsigned int q0y = pkbf(sf[base + 3], sf[base + 2]);
            unsigned int q1x = pkbf(sf[base + 5], sf[base + 4]);
            unsigned int q1y = pkbf(sf[base + 7], sf[base + 6]);
            unsigned int t0x = __shfl_xor(q0x, 32);
            unsigned int t0y = __shfl_xor(q0y, 32);
            unsigned int t1x = __shfl_xor(q1x, 32);
            unsigned int t1y = __shfl_xor(q1y, 32);
            union { unsigned int w[4]; short8 s8; } bu;
            bu.w[0] = h ? t1x : q0x;
            bu.w[1] = h ? t1y : q0y;
            bu.w[2] = h ? q1x : t0x;
            bu.w[3] = h ? q1y : t0y;
#pragma unroll
            for (int hc = 0; hc < 4; hc++) {
                int row = hc * 32 + l31;
                int slot = (kk * 2 + h) ^ (row & 7);
                short8 av = *(const short8*)&Vsb[row * 64 + slot * 8];
                ao[hc] = __builtin_amdgcn_mfma_f32_32x32x16_bf16(av, bu.s8, ao[hc], 0, 0, 0);
            }
        }
        cur ^= 1;
    }

    // epilogue
    const size_t BT = (size_t)B_ * T_;
    __syncthreads();                       // all compute done before aliasing smem
    if (lane < 32) {
        int grow = b * T_ + query;
        Mpart[(size_t)s * BT + grow] = m_i;
        Lpart[(size_t)s * BT + grow] = l_i;
    }
    ushort* Ot = smem;                     // [128 q][136]
#pragma unroll
    for (int hc = 0; hc < 4; hc++)
#pragma unroll
        for (int rq = 0; rq < 4; rq++) {
            uint2 w = make_uint2(
                ((unsigned int)f2bf(ao[hc][rq * 4 + 0])) | ((unsigned int)f2bf(ao[hc][rq * 4 + 1]) << 16),
                ((unsigned int)f2bf(ao[hc][rq * 4 + 2])) | ((unsigned int)f2bf(ao[hc][rq * 4 + 3]) << 16));
            *(uint2*)&Ot[(wave * 32 + l31) * 136 + hc * 32 + rq * 8 + h * 4] = w;
        }
    __syncthreads();
    {
        int qq = t >> 1, half = (t & 1) * 64;
        size_t row = (size_t)s * BT + b * T_ + q0 + qq;
        ushort* dst = Opart + row * H_ + half;
        const ushort* src = &Ot[qq * 136 + half];
#pragma unroll
        for (int j = 0; j < 8; j++)
            *(uint4*)(dst + j * 8) = *(const uint4*)(src + j * 8);
    }
}

// ---------------------------------------------------------------------------
// Kernel 4: combine split-K partials
// ---------------------------------------------------------------------------
__launch_bounds__(256)
__global__ void combine_kernel(const ushort* __restrict__ Opart,
                               const float* __restrict__ Mpart,
                               const float* __restrict__ Lpart,
                               float* __restrict__ out) {
    int t = threadIdx.x;
    int row = blockIdx.x * 2 + (t >> 7);
    int col = t & 127;
    const size_t BT = (size_t)B_ * T_;
    float m[S_], l[S_];
#pragma unroll
    for (int s = 0; s < S_; s++) {
        m[s] = Mpart[(size_t)s * BT + row];
        l[s] = Lpart[(size_t)s * BT + row];
    }
    float M = m[0];
#pragma unroll
    for (int s = 1; s < S_; s++) M = fmaxf(M, m[s]);
    float den = 0.0f, acc = 0.0f;
#pragma unroll
    for (int s = 0; s < S_; s++) {
        float w = __expf(m[s] - M);
        den += l[s] * w;
        acc += w * bf2f(Opart[((size_t)s * BT + row) * H_ + col]);
    }
    out[(size_t)row * H_ + col] = acc / den;
}

// ---------------------------------------------------------------------------
extern "C" void kernel_launch(void* const* d_in, const int* in_sizes, int n_in,
                              void* d_out, int out_size, void* d_ws, size_t ws_size,
                              hipStream_t stream) {
    (void)in_sizes; (void)n_in; (void)out_size; (void)ws_size;
    const float* k  = (const float*)d_in[0];
    const float* q  = (const float*)d_in[1];
    const float* v  = (const float*)d_in[2];
    const float* Wk = (const float*)d_in[3];
    const float* Wq = (const float*)d_in[4];
    const float* Wv = (const float*)d_in[5];

    ushort* wsu = (ushort*)d_ws;
    const size_t PROJ_ELEMS = (size_t)B_ * T_ * H_;        // 2,097,152
    ushort* kp  = wsu;
    ushort* qp  = wsu + PROJ_ELEMS;
    ushort* vpt = wsu + 2 * PROJ_ELEMS;
    ushort* Wt  = wsu + 3 * PROJ_ELEMS;                    // 393,216 ushorts
    char*  fbase = (char*)d_ws + (3 * PROJ_ELEMS + 393216) * sizeof(ushort);
    float* Mpart = (float*)fbase;                          // S_*B*T floats
    float* Lpart = Mpart + (size_t)S_ * B_ * T_;
    ushort* Opart = (ushort*)(Lpart + (size_t)S_ * B_ * T_);  // S_*B*T*H bf16

    prep_w_kernel<<<dim3((E_ * H_ + 255) / 256, 3), 256, 0, stream>>>(Wk, Wq, Wv, Wt);
    proj_kernel<<<dim3((B_ * T_) / 64, 3), 256, 0, stream>>>(k, q, v, Wt, kp, qp, vpt);
    attn_kernel<<<dim3(S_, T_ / 128, B_), 256, 0, stream>>>(kp, qp, vpt, Opart, Mpart, Lpart);
    combine_kernel<<<dim3(B_ * T_ / 2), 256, 0, stream>>>(Opart, Mpart, Lpart, (float*)d_out);
}